// Round 9
// baseline (135.437 us; speedup 1.0000x reference)
//
#include <hip/hip_runtime.h>
#include <hip/hip_bf16.h>

// LCN spiking net, round 9: 3 dispatches.
//  - Spiking update is identity; only t=T-1 matters -> 32 rows.
//  - Floor is ~102us of harness reset (measured R4/R6); my slice ~27us in R8
//    was ~half dispatch-boundary overhead -> cut 4 dispatches to 3 by pulling
//    layer 2 into the one-block-per-row tail (l2+l3+l4 = ~1230 LDS
//    wave-gathers/block at ~11cyc, ~5us: affordable; R6's 5450 was not).
//  - R4: grid barriers ~35us each -> never again. R6: big layers stay as
//    wide transposed GLOBAL gathers. R8: scatter STORES are fine, strided
//    READS are not -> l1 writes h2 row-major so the tail stages coalesced.

#define ROWS 32
#define TSTEPS 20
#define D0 14400
#define D1 7200
#define D2 3600
#define D3 1800
#define D4 900
#define D5 450
#define KNB 25

// K1: layer 0. Grid (8, ROWS), 256 threads. Stage x row in LDS, gather 900
// outputs per block, write h1t transposed.
__global__ __launch_bounds__(256)
void l0_stage(const float* __restrict__ x, float* __restrict__ h1t,
              const float* __restrict__ w, const float* __restrict__ bvec,
              const int* __restrict__ knn)
{
    __shared__ float s[D0];   // 57.6 KB
    const int r = blockIdx.y;
    const float* xrow = x + ((size_t)r * TSTEPS + (TSTEPS - 1)) * (size_t)D0;

    const float4* src = reinterpret_cast<const float4*>(xrow);
    float4* dst = reinterpret_cast<float4*>(s);
#pragma unroll 1
    for (int i = threadIdx.x; i < D0 / 4; i += 256)
        dst[i] = src[i];
    __syncthreads();

    const int j0 = blockIdx.x * 900;
#pragma unroll 1
    for (int j = j0 + threadIdx.x; j < j0 + 900; j += 256) {
        const int*   kn = knn + j * KNB;
        const float* ww = w   + j * KNB;
        float acc = bvec[j];
#pragma unroll
        for (int k = 0; k < KNB; ++k)
            acc += s[kn[k]] * ww[k];
        h1t[(j << 5) + r] = acc;   // transposed write
    }
}

// K2: layer 1, transposed gather h1t -> h2 ROW-MAJOR. Wave = 2 outputs x 32
// rows; gathers 2x128B coalesced; row-major scatter store (fire-and-forget).
__global__ __launch_bounds__(256)
void l1_t_rm(const float* __restrict__ pin, float* __restrict__ pout_rm,
             const float* __restrict__ w, const float* __restrict__ bvec,
             const int* __restrict__ knn)
{
    const int lane = threadIdx.x & 63;
    const int r  = lane & 31;
    const int jj = lane >> 5;
    const int nw = gridDim.x << 2;
#pragma unroll 1
    for (int jp = (blockIdx.x << 2) + (threadIdx.x >> 6); jp < D2 / 2; jp += nw) {
        const int j = (jp << 1) + jj;
        const int*   kn = knn + j * KNB;
        const float* ww = w   + j * KNB;
        float acc = bvec[j];
#pragma unroll
        for (int k = 0; k < KNB; ++k)
            acc += pin[(kn[k] << 5) + r] * ww[k];
        pout_rm[r * D2 + j] = acc;   // row-major
    }
}

// K3: tail = layer2 (3600->1800) + layer3 (1800->900) + layer4 (900->450)
// + FC (450->2). One block per row, 1024 threads. Coalesced stage of h2 row,
// ~1230 LDS wave-gathers, direct store to out. LDS: 27 KB.
__global__ __launch_bounds__(1024)
void tail32(const float* __restrict__ h2_rm,
            const float* __restrict__ w2, const float* __restrict__ b2, const int* __restrict__ knn2,
            const float* __restrict__ w3, const float* __restrict__ b3, const int* __restrict__ knn3,
            const float* __restrict__ w4, const float* __restrict__ b4, const int* __restrict__ knn4,
            const float* __restrict__ Wfc, const float* __restrict__ bfc,
            float* __restrict__ out)
{
    __shared__ float s2[D2];
    __shared__ float s3[D3];
    __shared__ float s4[D4];
    __shared__ float s5[D5];

    const int r = blockIdx.x;
    const float* hrow = h2_rm + (size_t)r * D2;

    // coalesced stage: 3600 floats
#pragma unroll 1
    for (int i = threadIdx.x; i < D2; i += 1024)
        s2[i] = hrow[i];
    __syncthreads();

#pragma unroll 1
    for (int j = threadIdx.x; j < D3; j += 1024) {
        const int*   kn = knn2 + j * KNB;
        const float* ww = w2   + j * KNB;
        float acc = b2[j];
#pragma unroll
        for (int k = 0; k < KNB; ++k)
            acc += s2[kn[k]] * ww[k];
        s3[j] = acc;
    }
    __syncthreads();

#pragma unroll 1
    for (int j = threadIdx.x; j < D4; j += 1024) {
        const int*   kn = knn3 + j * KNB;
        const float* ww = w3   + j * KNB;
        float acc = b3[j];
#pragma unroll
        for (int k = 0; k < KNB; ++k)
            acc += s3[kn[k]] * ww[k];
        s4[j] = acc;
    }
    __syncthreads();

#pragma unroll 1
    for (int j = threadIdx.x; j < D5; j += 1024) {
        const int*   kn = knn4 + j * KNB;
        const float* ww = w4   + j * KNB;
        float acc = b4[j];
#pragma unroll
        for (int k = 0; k < KNB; ++k)
            acc += s4[kn[k]] * ww[k];
        s5[j] = acc;
    }
    __syncthreads();

    const int lane = threadIdx.x & 63;
    const int wid  = threadIdx.x >> 6;
    if (wid < 2) {
        float p = 0.0f;
#pragma unroll 1
        for (int i = lane; i < D5; i += 64)
            p += s5[i] * Wfc[i * 2 + wid];
#pragma unroll
        for (int off = 32; off; off >>= 1)
            p += __shfl_down(p, off, 64);
        if (lane == 0)
            out[r * 2 + wid] = p + bfc[wid];
    }
}

extern "C" void kernel_launch(void* const* d_in, const int* in_sizes, int n_in,
                              void* d_out, int out_size, void* d_ws, size_t ws_size,
                              hipStream_t stream)
{
    const float* x    = (const float*)d_in[0];
    const float* w0   = (const float*)d_in[1];
    const float* b0   = (const float*)d_in[2];
    const int*   knn0 = (const int*)  d_in[3];
    const float* w1   = (const float*)d_in[4];
    const float* b1   = (const float*)d_in[5];
    const int*   knn1 = (const int*)  d_in[6];
    const float* w2   = (const float*)d_in[7];
    const float* b2   = (const float*)d_in[8];
    const int*   knn2 = (const int*)  d_in[9];
    const float* w3   = (const float*)d_in[10];
    const float* b3   = (const float*)d_in[11];
    const int*   knn3 = (const int*)  d_in[12];
    const float* w4   = (const float*)d_in[13];
    const float* b4   = (const float*)d_in[14];
    const int*   knn4 = (const int*)  d_in[15];
    const float* Wfc  = (const float*)d_in[16];
    const float* bfc  = (const float*)d_in[17];
    float* out = (float*)d_out;

    // ws (floats): h1t[D1][32] | h2_rm[32][D2]
    float* h1t   = (float*)d_ws;
    float* h2_rm = h1t + (size_t)D1 * ROWS;

    // K1: layer 0, x[:,T-1,:] -> h1t   (8 blocks/row)
    l0_stage<<<dim3(8, ROWS), dim3(256), 0, stream>>>(x, h1t, w0, b0, knn0);

    // K2: layer 1, h1t -> h2 row-major  (1800 pairs, 1 pair/wave)
    l1_t_rm<<<dim3(450), dim3(256), 0, stream>>>(h1t, h2_rm, w1, b1, knn1);

    // K3: layers 2+3+4+FC, one block per row, direct store to out
    tail32<<<dim3(ROWS), dim3(1024), 0, stream>>>(
        h2_rm, w2, b2, knn2, w3, b3, knn3, w4, b4, knn4, Wfc, bfc, out);
}

// Round 10
// 128.956 us; speedup vs baseline: 1.0503x; 1.0503x over previous
//
#include <hip/hip_runtime.h>
#include <hip/hip_bf16.h>

// LCN spiking net, FINAL (round 10) = round-8 structure, the measured optimum.
//  - Spiking update is identity (syn/mem zero-state) -> each layer is a
//    sparse gather-matvec + bias. Only t=T-1 reaches the output -> 32 rows.
//  - Measured landscape (dur_us): R1 one-block fused 202; R4 persistent+grid
//    barriers 307 (barrier ~35us each!); R6 all-LDS 1-block/row 148;
//    R9 3-dispatch 135; R3/R5/R7/R8 multi-dispatch 129-134. Optimum: 4
//    dispatches, wide transposed global gathers for big layers, small
//    one-block-per-row tail.
//  - Floor: ~102us of harness d_ws re-poison + input restore inside the
//    timed window (256MB fill at ~78% HBM peak) — untouchable.
//  - Layout lessons: knn indices shared across rows -> feature-major
//    h_t[d][32] makes every gather 2x128B coalesced; scatter STORES are
//    fire-and-forget but strided READS stall -> l2 writes row-major so the
//    tail stages coalesced.

#define ROWS 32
#define TSTEPS 20
#define D0 14400
#define D1 7200
#define D2 3600
#define D3 1800
#define D4 900
#define D5 450
#define KNB 25

// K1: layer 0. Grid (8, ROWS), 512 threads. Stage x row in LDS (57.6KB),
// gather 900 outputs per block, write h1t transposed. 8 waves/CU.
__global__ __launch_bounds__(512)
void l0_stage(const float* __restrict__ x, float* __restrict__ h1t,
              const float* __restrict__ w, const float* __restrict__ bvec,
              const int* __restrict__ knn)
{
    __shared__ float s[D0];
    const int r = blockIdx.y;
    const float* xrow = x + ((size_t)r * TSTEPS + (TSTEPS - 1)) * (size_t)D0;

    const float4* src = reinterpret_cast<const float4*>(xrow);
    float4* dst = reinterpret_cast<float4*>(s);
#pragma unroll 1
    for (int i = threadIdx.x; i < D0 / 4; i += 512)
        dst[i] = src[i];
    __syncthreads();

    const int j0 = blockIdx.x * 900;
#pragma unroll 1
    for (int j = j0 + threadIdx.x; j < j0 + 900; j += 512) {
        const int*   kn = knn + j * KNB;
        const float* ww = w   + j * KNB;
        float acc = bvec[j];
#pragma unroll
        for (int k = 0; k < KNB; ++k)
            acc += s[kn[k]] * ww[k];
        h1t[(j << 5) + r] = acc;   // transposed write
    }
}

// K2: layer 1, transposed gather h1t -> h2t. Wave = 2 outputs x 32 rows;
// each gather touches 2 contiguous 128B lines (L2-served, all CUs busy).
__global__ __launch_bounds__(256)
void layer_t_k(const float* __restrict__ pin, float* __restrict__ pout,
               const float* __restrict__ w, const float* __restrict__ bvec,
               const int* __restrict__ knn, int npairs)
{
    const int lane = threadIdx.x & 63;
    const int r  = lane & 31;
    const int jj = lane >> 5;
    const int nw = gridDim.x << 2;
#pragma unroll 1
    for (int jp = (blockIdx.x << 2) + (threadIdx.x >> 6); jp < npairs; jp += nw) {
        const int j = (jp << 1) + jj;
        const int*   kn = knn + j * KNB;
        const float* ww = w   + j * KNB;
        float acc = bvec[j];
#pragma unroll
        for (int k = 0; k < KNB; ++k)
            acc += pin[(kn[k] << 5) + r] * ww[k];
        pout[(j << 5) + r] = acc;
    }
}

// K3: layer 2, transposed gather writing ROW-MAJOR output (tail stages
// coalesced; scatter stores are fire-and-forget).
__global__ __launch_bounds__(256)
void layer_t_rm(const float* __restrict__ pin, float* __restrict__ pout_rm,
                const float* __restrict__ w, const float* __restrict__ bvec,
                const int* __restrict__ knn, int npairs, int dout)
{
    const int lane = threadIdx.x & 63;
    const int r  = lane & 31;
    const int jj = lane >> 5;
    const int nw = gridDim.x << 2;
#pragma unroll 1
    for (int jp = (blockIdx.x << 2) + (threadIdx.x >> 6); jp < npairs; jp += nw) {
        const int j = (jp << 1) + jj;
        const int*   kn = knn + j * KNB;
        const float* ww = w   + j * KNB;
        float acc = bvec[j];
#pragma unroll
        for (int k = 0; k < KNB; ++k)
            acc += pin[(kn[k] << 5) + r] * ww[k];
        pout_rm[r * dout + j] = acc;   // row-major scatter store
    }
}

// K4: tail = layer3 (1800->900) + layer4 (900->450) + FC (450->2).
// One block per row, 1024 threads; coalesced stage of h3 row, ~530 LDS
// wave-gathers, direct store to out (no atomics, no memset).
__global__ __launch_bounds__(1024)
void tail32(const float* __restrict__ h3_rm,
            const float* __restrict__ w3, const float* __restrict__ b3, const int* __restrict__ knn3,
            const float* __restrict__ w4, const float* __restrict__ b4, const int* __restrict__ knn4,
            const float* __restrict__ Wfc, const float* __restrict__ bfc,
            float* __restrict__ out)
{
    __shared__ float s3[D3];
    __shared__ float s4[D4];
    __shared__ float s5[D5];

    const int r = blockIdx.x;
    const float* hrow = h3_rm + (size_t)r * D3;

#pragma unroll 1
    for (int i = threadIdx.x; i < D3; i += 1024)
        s3[i] = hrow[i];
    __syncthreads();

#pragma unroll 1
    for (int j = threadIdx.x; j < D4; j += 1024) {
        const int*   kn = knn3 + j * KNB;
        const float* ww = w3   + j * KNB;
        float acc = b3[j];
#pragma unroll
        for (int k = 0; k < KNB; ++k)
            acc += s3[kn[k]] * ww[k];
        s4[j] = acc;
    }
    __syncthreads();

#pragma unroll 1
    for (int j = threadIdx.x; j < D5; j += 1024) {
        const int*   kn = knn4 + j * KNB;
        const float* ww = w4   + j * KNB;
        float acc = b4[j];
#pragma unroll
        for (int k = 0; k < KNB; ++k)
            acc += s4[kn[k]] * ww[k];
        s5[j] = acc;
    }
    __syncthreads();

    const int lane = threadIdx.x & 63;
    const int wid  = threadIdx.x >> 6;
    if (wid < 2) {
        float p = 0.0f;
#pragma unroll 1
        for (int i = lane; i < D5; i += 64)
            p += s5[i] * Wfc[i * 2 + wid];
#pragma unroll
        for (int off = 32; off; off >>= 1)
            p += __shfl_down(p, off, 64);
        if (lane == 0)
            out[r * 2 + wid] = p + bfc[wid];
    }
}

extern "C" void kernel_launch(void* const* d_in, const int* in_sizes, int n_in,
                              void* d_out, int out_size, void* d_ws, size_t ws_size,
                              hipStream_t stream)
{
    const float* x    = (const float*)d_in[0];
    const float* w0   = (const float*)d_in[1];
    const float* b0   = (const float*)d_in[2];
    const int*   knn0 = (const int*)  d_in[3];
    const float* w1   = (const float*)d_in[4];
    const float* b1   = (const float*)d_in[5];
    const int*   knn1 = (const int*)  d_in[6];
    const float* w2   = (const float*)d_in[7];
    const float* b2   = (const float*)d_in[8];
    const int*   knn2 = (const int*)  d_in[9];
    const float* w3   = (const float*)d_in[10];
    const float* b3   = (const float*)d_in[11];
    const int*   knn3 = (const int*)  d_in[12];
    const float* w4   = (const float*)d_in[13];
    const float* b4   = (const float*)d_in[14];
    const int*   knn4 = (const int*)  d_in[15];
    const float* Wfc  = (const float*)d_in[16];
    const float* bfc  = (const float*)d_in[17];
    float* out = (float*)d_out;

    // ws (floats): h1t[D1][32] | h2t[D2][32] | h3_rm[32][D3]
    float* h1t   = (float*)d_ws;
    float* h2t   = h1t + (size_t)D1 * ROWS;
    float* h3_rm = h2t + (size_t)D2 * ROWS;

    // K1: layer 0, x[:,T-1,:] -> h1t   (8 blocks/row, 512 threads)
    l0_stage<<<dim3(8, ROWS), dim3(512), 0, stream>>>(x, h1t, w0, b0, knn0);

    // K2: layer 1, h1t -> h2t  (1800 pairs, 1 pair/wave)
    layer_t_k<<<dim3(450), dim3(256), 0, stream>>>(h1t, h2t, w1, b1, knn1, D2 / 2);

    // K3: layer 2, h2t -> h3 row-major  (900 pairs)
    layer_t_rm<<<dim3(225), dim3(256), 0, stream>>>(h2t, h3_rm, w2, b2, knn2, D3 / 2, D3);

    // K4: layers 3+4+FC, one block per row, direct store to out
    tail32<<<dim3(ROWS), dim3(1024), 0, stream>>>(
        h3_rm, w3, b3, knn3, w4, b4, knn4, Wfc, bfc, out);
}